// Round 5
// baseline (1125.476 us; speedup 1.0000x reference)
//
#include <hip/hip_runtime.h>
#include <hip/hip_cooperative_groups.h>

namespace cg = cooperative_groups;

#define SCAP_EGO 8192   // staging cap per 256-node bin (mean 6144)
#define SCAP_E   4096   // mean 3072

typedef unsigned short ushort_t;
typedef unsigned int uint_t;
typedef __attribute__((ext_vector_type(8))) short bf16x8;
typedef __attribute__((ext_vector_type(4))) float f32x4;

__device__ inline float lo16(uint_t u) { return __uint_as_float(u << 16); }
__device__ inline float hi16(uint_t u) { return __uint_as_float(u & 0xFFFF0000u); }
__device__ inline ushort_t f2bf(float f) {
    uint_t i = __float_as_uint(f);
    return (ushort_t)((i + 0x7FFFu + ((i >> 16) & 1u)) >> 16);
}
__device__ inline uint_t pack2(float a, float b) {
    return (uint_t)f2bf(a) | ((uint_t)f2bf(b) << 16);
}

// ============ device phase bodies (shared by mega + fallback path) ========

__device__ __forceinline__ void dev_prep_item(int i,
    const float* __restrict__ x, ushort_t* __restrict__ xb, int n8,
    const float* __restrict__ W0, const float* __restrict__ W1,
    const float* __restrict__ W2, const float* __restrict__ W3,
    ushort_t* __restrict__ T0, ushort_t* __restrict__ T1,
    ushort_t* __restrict__ T2, ushort_t* __restrict__ T3,
    int* __restrict__ z)
{
    if (i < 128) ((int4*)z)[i] = make_int4(0, 0, 0, 0);
    if (i < n8) {
        const float4* p = (const float4*)(x + (size_t)i * 8);
        float4 a = p[0], b = p[1];
        uint4 o;
        o.x = pack2(a.x, a.y); o.y = pack2(a.z, a.w);
        o.z = pack2(b.x, b.y); o.w = pack2(b.z, b.w);
        *(uint4*)(xb + (size_t)i * 8) = o;
    }
    if (i < 49152) {
        int mi = i >> 14;
        int r = i & 16383;
        int n = r >> 7, k = r & 127;
        const float* W = mi == 0 ? W0 : (mi == 1 ? W1 : W2);
        ushort_t* T = mi == 0 ? T0 : (mi == 1 ? T1 : T2);
        T[n * 128 + k] = f2bf(W[k * 128 + n]);
    } else if (i < 49152 + 6144) {
        int r = i - 49152;
        int n = r >> 7, k = r & 127;
        T3[n * 128 + k] = (n < 47) ? f2bf(W3[k * 47 + n]) : (ushort_t)0;
    }
}

__device__ __forceinline__ void dev_bin_chunk(int c, int nc1,
    const int* __restrict__ d1, const int* __restrict__ s1, int n1,
    int2* __restrict__ st1, int* __restrict__ cur1, int scap1,
    const int* __restrict__ d2, const int* __restrict__ s2, int n2,
    int2* __restrict__ st2, int* __restrict__ cur2, int scap2,
    int* bcnt, int* gbase, int t)
{
    const int* dst; const int* src; int nE, scap; int* bincur; int2* stage; int bid;
    if (c < nc1) {
        dst = d1; src = s1; nE = n1; scap = scap1; bincur = cur1; stage = st1;
        bid = c;
    } else {
        dst = d2; src = s2; nE = n2; scap = scap2; bincur = cur2; stage = st2;
        bid = c - nc1;
    }
    bcnt[t] = 0;
    __syncthreads();
    int base = bid * 4096;
    int d[16], s[16], l[16];
#pragma unroll
    for (int i = 0; i < 16; i++) {
        int e = base + t + i * 256;
        if (e < nE) {
            d[i] = dst[e]; s[i] = src[e];
            l[i] = atomicAdd(&bcnt[d[i] >> 8], 1);
        } else d[i] = -1;
    }
    __syncthreads();
    if (bcnt[t]) gbase[t] = atomicAdd(&bincur[t], bcnt[t]);
    __syncthreads();
#pragma unroll
    for (int i = 0; i < 16; i++) {
        if (d[i] >= 0) {
            int b = d[i] >> 8;
            int slot = gbase[b] + l[i];
            if (slot < scap) stage[(size_t)b * scap + slot] = make_int2(d[i], s[i]);
        }
    }
    __syncthreads();
}

__device__ __forceinline__ void dev_csr_bin(int c, int NB,
    const int* __restrict__ cur1, const int2* __restrict__ st1, int scap1,
    int* __restrict__ cnt1, int* __restrict__ rp1, int* __restrict__ pk1,
    const int* __restrict__ cur2, const int2* __restrict__ st2, int scap2,
    int* __restrict__ cnt2, int* __restrict__ rp2, int* __restrict__ pk2,
    int* sc, int* wcur, int t)
{
    const int* bincur; const int2* stage; int scap;
    int* cnt; int* rowptr; int* packed; int b;
    if (c < NB) {
        bincur = cur1; stage = st1; scap = scap1;
        cnt = cnt1; rowptr = rp1; packed = pk1; b = c;
    } else {
        bincur = cur2; stage = st2; scap = scap2;
        cnt = cnt2; rowptr = rp2; packed = pk2; b = c - NB;
    }
    int m = bincur[b]; if (m > scap) m = scap;
    const int2* st = stage + (size_t)b * scap;
    sc[t] = 0;
    __syncthreads();
    for (int e = t; e < m; e += 256) atomicAdd(&sc[st[e].x & 255], 1);
    __syncthreads();
    int v = sc[t];
    __syncthreads();
    sc[t] = v;
    __syncthreads();
    for (int off = 1; off < 256; off <<= 1) {
        int y = (t >= off) ? sc[t - off] : 0;
        __syncthreads();
        sc[t] += y;
        __syncthreads();
    }
    int excl = sc[t] - v;
    cnt[b * 256 + t] = v;
    rowptr[b * 256 + t] = b * scap + excl;
    wcur[t] = excl;
    __syncthreads();
    int* pk = packed + (size_t)b * scap;
    for (int e = t; e < m; e += 256) {
        int2 p2 = st[e];
        int slot = atomicAdd(&wcur[p2.x & 255], 1);
        pk[slot] = p2.y;
    }
    __syncthreads();
}

// fused gather(16 nodes) -> LDS -> MFMA 128->128 + relu  (round-3 verified)
__device__ __forceinline__ void dev_f16(int tile, int SELF,
    const ushort_t* __restrict__ X,
    const int* __restrict__ cnt, const int* __restrict__ rowptr,
    const int* __restrict__ packed,
    const ushort_t* __restrict__ WT, const float* __restrict__ bias,
    ushort_t* __restrict__ outb, int nrows, float scale,
    ushort_t As[16][136], int t)
{
    int g = t >> 4, lane = t & 15;
    int blockBase = tile * 16;
    int n = blockBase + g;
    const ushort_t* base = X + lane * 8;
    float a[8];
#pragma unroll
    for (int i = 0; i < 8; i++) a[i] = 0.f;
    if (n < nrows) {
        int len = cnt[n];
        const int* row = packed + rowptr[n];
        int e = 0;
        for (; e + 3 < len; e += 4) {
            uint4 w0 = *(const uint4*)(base + (size_t)row[e] * 128);
            uint4 w1 = *(const uint4*)(base + (size_t)row[e + 1] * 128);
            uint4 w2 = *(const uint4*)(base + (size_t)row[e + 2] * 128);
            uint4 w3 = *(const uint4*)(base + (size_t)row[e + 3] * 128);
            a[0] += lo16(w0.x) + lo16(w1.x) + lo16(w2.x) + lo16(w3.x);
            a[1] += hi16(w0.x) + hi16(w1.x) + hi16(w2.x) + hi16(w3.x);
            a[2] += lo16(w0.y) + lo16(w1.y) + lo16(w2.y) + lo16(w3.y);
            a[3] += hi16(w0.y) + hi16(w1.y) + hi16(w2.y) + hi16(w3.y);
            a[4] += lo16(w0.z) + lo16(w1.z) + lo16(w2.z) + lo16(w3.z);
            a[5] += hi16(w0.z) + hi16(w1.z) + hi16(w2.z) + hi16(w3.z);
            a[6] += lo16(w0.w) + lo16(w1.w) + lo16(w2.w) + lo16(w3.w);
            a[7] += hi16(w0.w) + hi16(w1.w) + hi16(w2.w) + hi16(w3.w);
        }
        for (; e < len; e++) {
            uint4 w = *(const uint4*)(base + (size_t)row[e] * 128);
            a[0] += lo16(w.x); a[1] += hi16(w.x);
            a[2] += lo16(w.y); a[3] += hi16(w.y);
            a[4] += lo16(w.z); a[5] += hi16(w.z);
            a[6] += lo16(w.w); a[7] += hi16(w.w);
        }
        if (SELF) {
            uint4 w = *(const uint4*)(base + (size_t)n * 128);
            a[0] += lo16(w.x); a[1] += hi16(w.x);
            a[2] += lo16(w.y); a[3] += hi16(w.y);
            a[4] += lo16(w.z); a[5] += hi16(w.z);
            a[6] += lo16(w.w); a[7] += hi16(w.w);
        }
    }
    uint4 o;
    o.x = pack2(a[0] * scale, a[1] * scale);
    o.y = pack2(a[2] * scale, a[3] * scale);
    o.z = pack2(a[4] * scale, a[5] * scale);
    o.w = pack2(a[6] * scale, a[7] * scale);
    *(uint4*)&As[g][lane * 8] = o;
    __syncthreads();
    // MFMA: 16 rows x 128 cols; wave w -> col-tiles 2w, 2w+1
    int wave = t >> 6, l64 = t & 63;
    int m = l64 & 15, quad = l64 >> 4;
    bf16x8 afr[4];
#pragma unroll
    for (int kt = 0; kt < 4; kt++)
        afr[kt] = *(const bf16x8*)&As[m][kt * 32 + quad * 8];
    f32x4 acc[2];
#pragma unroll
    for (int j = 0; j < 2; j++) acc[j] = (f32x4){0.f, 0.f, 0.f, 0.f};
#pragma unroll
    for (int j = 0; j < 2; j++) {
        int ct = wave * 2 + j;
#pragma unroll
        for (int kt = 0; kt < 4; kt++) {
            bf16x8 b = *(const bf16x8*)(WT + (size_t)(ct * 16 + m) * 128
                                           + kt * 32 + quad * 8);
            acc[j] = __builtin_amdgcn_mfma_f32_16x16x32_bf16(afr[kt], b, acc[j], 0, 0, 0);
        }
    }
#pragma unroll
    for (int j = 0; j < 2; j++) {
        int col = (wave * 2 + j) * 16 + m;
        float bb = bias[col];
#pragma unroll
        for (int r = 0; r < 4; r++) {
            int row = blockBase + quad * 4 + r;
            if (row < nrows) {
                float v = acc[j][r] + bb;
                v = fmaxf(v, 0.f);
                outb[(size_t)row * 128 + col] = f2bf(v);
            }
        }
    }
    __syncthreads();   // protect As for next persistent iteration
}

// fused gather + MFMA 128->47 + log_softmax (round-3 verified, all-thread-safe)
__device__ __forceinline__ void dev_f47(int tile,
    const ushort_t* __restrict__ X,
    const int* __restrict__ cnt, const int* __restrict__ rowptr,
    const int* __restrict__ packed,
    const ushort_t* __restrict__ WT, const float* __restrict__ bias,
    float* __restrict__ out, int nrows,
    ushort_t As[16][136], int t)
{
    int g = t >> 4, lane = t & 15;
    int blockBase = tile * 16;
    int n = blockBase + g;
    const ushort_t* base = X + lane * 8;
    float a[8];
#pragma unroll
    for (int i = 0; i < 8; i++) a[i] = 0.f;
    if (n < nrows) {
        int len = cnt[n];
        const int* row = packed + rowptr[n];
        int e = 0;
        for (; e + 3 < len; e += 4) {
            uint4 w0 = *(const uint4*)(base + (size_t)row[e] * 128);
            uint4 w1 = *(const uint4*)(base + (size_t)row[e + 1] * 128);
            uint4 w2 = *(const uint4*)(base + (size_t)row[e + 2] * 128);
            uint4 w3 = *(const uint4*)(base + (size_t)row[e + 3] * 128);
            a[0] += lo16(w0.x) + lo16(w1.x) + lo16(w2.x) + lo16(w3.x);
            a[1] += hi16(w0.x) + hi16(w1.x) + hi16(w2.x) + hi16(w3.x);
            a[2] += lo16(w0.y) + lo16(w1.y) + lo16(w2.y) + lo16(w3.y);
            a[3] += hi16(w0.y) + hi16(w1.y) + hi16(w2.y) + hi16(w3.y);
            a[4] += lo16(w0.z) + lo16(w1.z) + lo16(w2.z) + lo16(w3.z);
            a[5] += hi16(w0.z) + hi16(w1.z) + hi16(w2.z) + hi16(w3.z);
            a[6] += lo16(w0.w) + lo16(w1.w) + lo16(w2.w) + lo16(w3.w);
            a[7] += hi16(w0.w) + hi16(w1.w) + hi16(w2.w) + hi16(w3.w);
        }
        for (; e < len; e++) {
            uint4 w = *(const uint4*)(base + (size_t)row[e] * 128);
            a[0] += lo16(w.x); a[1] += hi16(w.x);
            a[2] += lo16(w.y); a[3] += hi16(w.y);
            a[4] += lo16(w.z); a[5] += hi16(w.z);
            a[6] += lo16(w.w); a[7] += hi16(w.w);
        }
        // GIN self term
        uint4 w = *(const uint4*)(base + (size_t)n * 128);
        a[0] += lo16(w.x); a[1] += hi16(w.x);
        a[2] += lo16(w.y); a[3] += hi16(w.y);
        a[4] += lo16(w.z); a[5] += hi16(w.z);
        a[6] += lo16(w.w); a[7] += hi16(w.w);
    }
    uint4 o;
    o.x = pack2(a[0], a[1]);
    o.y = pack2(a[2], a[3]);
    o.z = pack2(a[4], a[5]);
    o.w = pack2(a[6], a[7]);
    *(uint4*)&As[g][lane * 8] = o;
    __syncthreads();
    int wave = t >> 6;
    if (wave == 0) {
        int l64 = t & 63;
        int m = l64 & 15, quad = l64 >> 4;
        bf16x8 afr[4];
#pragma unroll
        for (int kt = 0; kt < 4; kt++)
            afr[kt] = *(const bf16x8*)&As[m][kt * 32 + quad * 8];
        f32x4 acc[3];
#pragma unroll
        for (int ct = 0; ct < 3; ct++) acc[ct] = (f32x4){0.f, 0.f, 0.f, 0.f};
#pragma unroll
        for (int ct = 0; ct < 3; ct++) {
#pragma unroll
            for (int kt = 0; kt < 4; kt++) {
                bf16x8 b = *(const bf16x8*)(WT + (size_t)(ct * 16 + m) * 128
                                               + kt * 32 + quad * 8);
                acc[ct] = __builtin_amdgcn_mfma_f32_16x16x32_bf16(afr[kt], b, acc[ct], 0, 0, 0);
            }
        }
        int c0 = m, c1 = 16 + m, c2 = 32 + m;
        bool has2 = (c2 < 47);
        float b0 = bias[c0], b1 = bias[c1], b2 = has2 ? bias[c2] : 0.f;
#pragma unroll
        for (int r = 0; r < 4; r++) {
            int row = blockBase + quad * 4 + r;
            float v0 = acc[0][r] + b0;
            float v1 = acc[1][r] + b1;
            float v2 = has2 ? (acc[2][r] + b2) : -INFINITY;
            float mx = fmaxf(fmaxf(v0, v1), v2);
#pragma unroll
            for (int off = 8; off; off >>= 1) mx = fmaxf(mx, __shfl_xor(mx, off, 64));
            float s = __expf(v0 - mx) + __expf(v1 - mx) + (has2 ? __expf(v2 - mx) : 0.f);
#pragma unroll
            for (int off = 8; off; off >>= 1) s += __shfl_xor(s, off, 64);
            float lse = mx + __logf(s);
            if (row < nrows) {
                float* o2 = out + (size_t)row * 47;
                o2[c0] = v0 - lse;
                o2[c1] = v1 - lse;
                if (has2) o2[c2] = v2 - lse;
            }
        }
    }
    __syncthreads();
}

// ======================== persistent cooperative mega-kernel ==============
struct MegaP {
    const float* x_in; const int* edge; const int* ego;
    const float *W0, *W1, *W2, *W3;
    const float *bE0, *bG0, *bE1, *bG1;
    float* out;
    ushort_t *Xb, *G, *H, *T0, *T1, *T2, *T3;
    int *cnt_ego, *rp_ego, *pk_ego, *cnt_edge, *rp_edge, *pk_edge, *bincur;
    int2 *st_ego, *st_edge;
    int N, E, EGO_E, NB, n8; float invN;
};

__global__ __launch_bounds__(256, 8) void mega(MegaP p)
{
    cg::grid_group grid = cg::this_grid();
    __shared__ int sA[256], sB[256];
    __shared__ ushort_t As[16][136];
    int t = threadIdx.x, bid = blockIdx.x, nb = gridDim.x;
    int gsz = nb * 256, tix = bid * 256 + t;

    // P0: prep (covers bf16 convert, weight transpose, cursor zero)
    for (int i = tix; i < p.n8; i += gsz)
        dev_prep_item(i, p.x_in, p.Xb, p.n8, p.W0, p.W1, p.W2, p.W3,
                      p.T0, p.T1, p.T2, p.T3, p.bincur);
    grid.sync();

    // P1: bin edges of both graphs
    int nc1 = (p.EGO_E + 4095) >> 12, nc2 = (p.E + 4095) >> 12;
    for (int c = bid; c < nc1 + nc2; c += nb)
        dev_bin_chunk(c, nc1,
                      p.ego, p.ego + p.EGO_E, p.EGO_E, p.st_ego, p.bincur, SCAP_EGO,
                      p.edge + p.E, p.edge, p.E, p.st_edge, p.bincur + 256, SCAP_E,
                      sA, sB, t);
    grid.sync();

    // P2: per-bin counting sort -> packed CSR
    for (int c = bid; c < 2 * p.NB; c += nb)
        dev_csr_bin(c, p.NB,
                    p.bincur, p.st_ego, SCAP_EGO, p.cnt_ego, p.rp_ego, p.pk_ego,
                    p.bincur + 256, p.st_edge, SCAP_E, p.cnt_edge, p.rp_edge, p.pk_edge,
                    sA, sB, t);
    grid.sync();

    // P3..P6: the 4 network layers
    int nt = (p.N + 15) >> 4;
    for (int tile = bid; tile < nt; tile += nb)
        dev_f16(tile, 0, p.Xb, p.cnt_ego, p.rp_ego, p.pk_ego,
                p.T0, p.bE0, p.H, p.N, p.invN, As, t);
    grid.sync();
    for (int tile = bid; tile < nt; tile += nb)
        dev_f16(tile, 1, p.H, p.cnt_edge, p.rp_edge, p.pk_edge,
                p.T1, p.bG0, p.G, p.N, 1.f, As, t);
    grid.sync();
    for (int tile = bid; tile < nt; tile += nb)
        dev_f16(tile, 0, p.G, p.cnt_ego, p.rp_ego, p.pk_ego,
                p.T2, p.bE1, p.H, p.N, p.invN, As, t);
    grid.sync();
    for (int tile = bid; tile < nt; tile += nb)
        dev_f47(tile, p.H, p.cnt_edge, p.rp_edge, p.pk_edge,
                p.T3, p.bG1, p.out, p.N, As, t);
}

// ======================== fallback (round-3) kernels ======================
__global__ __launch_bounds__(256) void k_prep(
    const float* x, ushort_t* xb, int n8,
    const float* W0, const float* W1, const float* W2, const float* W3,
    ushort_t* T0, ushort_t* T1, ushort_t* T2, ushort_t* T3, int* z)
{
    int i = blockIdx.x * 256 + threadIdx.x;
    dev_prep_item(i, x, xb, n8, W0, W1, W2, W3, T0, T1, T2, T3, z);
}

__global__ __launch_bounds__(256) void k_bin(
    const int* d1, const int* s1, int n1, int nb1, int* cur1, int2* st1, int scap1,
    const int* d2, const int* s2, int n2, int* cur2, int2* st2, int scap2)
{
    __shared__ int bcnt[256], gbase[256];
    dev_bin_chunk(blockIdx.x, nb1, d1, s1, n1, st1, cur1, scap1,
                  d2, s2, n2, st2, cur2, scap2, bcnt, gbase, threadIdx.x);
}

__global__ __launch_bounds__(256) void k_csr(
    const int* cur1, const int2* st1, int scap1, int* cnt1, int* rp1, int* pk1,
    const int* cur2, const int2* st2, int scap2, int* cnt2, int* rp2, int* pk2,
    int NB)
{
    __shared__ int sc[256], wcur[256];
    dev_csr_bin(blockIdx.x, NB, cur1, st1, scap1, cnt1, rp1, pk1,
                cur2, st2, scap2, cnt2, rp2, pk2, sc, wcur, threadIdx.x);
}

__global__ __launch_bounds__(256, 8) void k_f16(
    const ushort_t* X, const int* cnt, const int* rp, const int* pk,
    const ushort_t* WT, const float* bias, ushort_t* outb, int nrows,
    float scale, int SELF)
{
    __shared__ ushort_t As[16][136];
    dev_f16(blockIdx.x, SELF, X, cnt, rp, pk, WT, bias, outb, nrows, scale,
            As, threadIdx.x);
}

__global__ __launch_bounds__(256, 8) void k_f47(
    const ushort_t* X, const int* cnt, const int* rp, const int* pk,
    const ushort_t* WT, const float* bias, float* out, int nrows)
{
    __shared__ ushort_t As[16][136];
    dev_f47(blockIdx.x, X, cnt, rp, pk, WT, bias, out, nrows, As, threadIdx.x);
}

// ============================== host ======================================
extern "C" void kernel_launch(void* const* d_in, const int* in_sizes, int n_in,
                              void* d_out, int out_size, void* d_ws, size_t ws_size,
                              hipStream_t stream) {
    const float* x_in   = (const float*)d_in[0];    // fp32 [N,128]
    const int*   edge   = (const int*)d_in[1];      // [2,E]  row0=src row1=tgt
    const int*   ego    = (const int*)d_in[2];      // [2,EGO_E] row0=dst row1=src
    const float* W_ego0 = (const float*)d_in[3];
    const float* b_ego0 = (const float*)d_in[4];
    const float* W_gin0 = (const float*)d_in[5];
    const float* b_gin0 = (const float*)d_in[6];
    const float* W_ego1 = (const float*)d_in[7];
    const float* b_ego1 = (const float*)d_in[8];
    const float* W_gin1 = (const float*)d_in[9];
    const float* b_gin1 = (const float*)d_in[10];
    float* out = (float*)d_out;                     // fp32 [N,47]

    const int N     = in_sizes[0] / 128;
    const int E     = in_sizes[1] / 2;
    const int EGO_E = in_sizes[2] / 2;
    const float invN = 1.0f / (float)N;
    const int NB    = (N + 255) >> 8;               // 256-node bins
    const int n8    = N * 128 / 8;

    // ---- workspace layout (~69 MB) ----
    const size_t NBELEM = (size_t)N * 128;
    ushort_t* Xb = (ushort_t*)d_ws;                 // bf16 [N,128]
    ushort_t* G  = Xb + NBELEM;                     // ping
    ushort_t* H  = G + NBELEM;                      // pong
    ushort_t* T0 = H + NBELEM;
    ushort_t* T1 = T0 + 16384;
    ushort_t* T2 = T1 + 16384;
    ushort_t* T3 = T2 + 16384;                      // [48][128]
    int* ip = (int*)(T3 + 6144);
    int* cnt_ego   = ip;             ip += NB * 256;
    int* rp_ego    = ip;             ip += NB * 256;
    int* cnt_edge  = ip;             ip += NB * 256;
    int* rp_edge   = ip;             ip += NB * 256;
    int* bincur    = ip;             ip += 512;     // [0..255]=ego, [256..511]=edge
    int2* stage_ego  = (int2*)ip;    ip += (size_t)NB * SCAP_EGO * 2;
    int*  pk_ego     = ip;           ip += (size_t)NB * SCAP_EGO;
    int2* stage_edge = (int2*)ip;    ip += (size_t)NB * SCAP_E * 2;
    int*  pk_edge    = ip;           ip += (size_t)NB * SCAP_E;

    MegaP P;
    P.x_in = x_in; P.edge = edge; P.ego = ego;
    P.W0 = W_ego0; P.W1 = W_gin0; P.W2 = W_ego1; P.W3 = W_gin1;
    P.bE0 = b_ego0; P.bG0 = b_gin0; P.bE1 = b_ego1; P.bG1 = b_gin1;
    P.out = out;
    P.Xb = Xb; P.G = G; P.H = H;
    P.T0 = T0; P.T1 = T1; P.T2 = T2; P.T3 = T3;
    P.cnt_ego = cnt_ego; P.rp_ego = rp_ego; P.pk_ego = pk_ego;
    P.cnt_edge = cnt_edge; P.rp_edge = rp_edge; P.pk_edge = pk_edge;
    P.bincur = bincur; P.st_ego = stage_ego; P.st_edge = stage_edge;
    P.N = N; P.E = E; P.EGO_E = EGO_E; P.NB = NB; P.n8 = n8; P.invN = invN;

    // cooperative grid size: co-resident blocks only (query once)
    static int coopGrid = 0;
    if (coopGrid == 0) {
        int dev = 0; (void)hipGetDevice(&dev);
        hipDeviceProp_t prop;
        int nCU = 256;
        if (hipGetDeviceProperties(&prop, dev) == hipSuccess &&
            prop.multiProcessorCount > 0)
            nCU = prop.multiProcessorCount;
        int mab = 0;
        if (hipOccupancyMaxActiveBlocksPerMultiprocessor(&mab, mega, 256, 0)
                != hipSuccess || mab < 1)
            mab = 1;
        long g = (long)mab * nCU;
        if (g > 2048) g = 2048;
        coopGrid = (int)g;
    }

    void* kargs[] = { (void*)&P };
    hipError_t err = hipLaunchCooperativeKernel((const void*)mega,
                                                dim3(coopGrid), dim3(256),
                                                kargs, 0, stream);
    if (err != hipSuccess) {
        (void)hipGetLastError();   // clear, use round-3 multi-launch path
        const int gFused = (N + 15) / 16;
        const int gBinE  = (EGO_E + 4095) / 4096;
        const int gBinF  = (E + 4095) / 4096;
        const int gCvt   = (n8 + 255) / 256;
        k_prep<<<gCvt, 256, 0, stream>>>(x_in, Xb, n8,
                                         W_ego0, W_gin0, W_ego1, W_gin1,
                                         T0, T1, T2, T3, bincur);
        k_bin<<<gBinE + gBinF, 256, 0, stream>>>(
            ego, ego + EGO_E, EGO_E, gBinE, bincur, stage_ego, SCAP_EGO,
            edge + E, edge, E, bincur + 256, stage_edge, SCAP_E);
        k_csr<<<2 * NB, 256, 0, stream>>>(
            bincur, stage_ego, SCAP_EGO, cnt_ego, rp_ego, pk_ego,
            bincur + 256, stage_edge, SCAP_E, cnt_edge, rp_edge, pk_edge, NB);
        k_f16<<<gFused, 256, 0, stream>>>(Xb, cnt_ego, rp_ego, pk_ego,
                                          T0, b_ego0, H, N, invN, 0);
        k_f16<<<gFused, 256, 0, stream>>>(H, cnt_edge, rp_edge, pk_edge,
                                          T1, b_gin0, G, N, 1.f, 1);
        k_f16<<<gFused, 256, 0, stream>>>(G, cnt_ego, rp_ego, pk_ego,
                                          T2, b_ego1, H, N, invN, 0);
        k_f47<<<gFused, 256, 0, stream>>>(H, cnt_edge, rp_edge, pk_edge,
                                          T3, b_gin1, out, N);
    }
}

// Round 6
// 714.063 us; speedup vs baseline: 1.5762x; 1.5762x over previous
//
#include <hip/hip_runtime.h>

#define SCAP_EGO 8192   // staging cap per 256-node bin (mean 6144)
#define SCAP_E   4096   // mean 3072

typedef unsigned short ushort_t;
typedef unsigned int uint_t;
typedef __attribute__((ext_vector_type(8))) short bf16x8;
typedef __attribute__((ext_vector_type(4))) float f32x4;

__device__ inline float lo16(uint_t u) { return __uint_as_float(u << 16); }
__device__ inline float hi16(uint_t u) { return __uint_as_float(u & 0xFFFF0000u); }
__device__ inline ushort_t f2bf(float f) {
    uint_t i = __float_as_uint(f);
    return (ushort_t)((i + 0x7FFFu + ((i >> 16) & 1u)) >> 16);
}
__device__ inline uint_t pack2(float a, float b) {
    return (uint_t)f2bf(a) | ((uint_t)f2bf(b) << 16);
}

// ======== zeroK: zero bincur[512] + barrier counter/generation ========
__global__ __launch_bounds__(256) void zeroK(int* __restrict__ z)
{
    for (int i = threadIdx.x; i < 516; i += 256) z[i] = 0;
}

// ======== hand-rolled grid barrier (regular launch, co-resident grid) ====
// All gridDim.x blocks must be co-resident (grid << 2048 at 8 blk/CU).
__device__ __forceinline__ void grid_barrier(int* bar, int* gen, int t)
{
    __threadfence();            // release: all block's prior writes device-visible
    __syncthreads();
    if (t == 0) {
        int g = __hip_atomic_load(gen, __ATOMIC_RELAXED, __HIP_MEMORY_SCOPE_AGENT);
        int a = __hip_atomic_fetch_add(bar, 1, __ATOMIC_ACQ_REL, __HIP_MEMORY_SCOPE_AGENT);
        if (a == (int)gridDim.x - 1) {
            __hip_atomic_store(bar, 0, __ATOMIC_RELAXED, __HIP_MEMORY_SCOPE_AGENT);
            __hip_atomic_store(gen, g + 1, __ATOMIC_RELEASE, __HIP_MEMORY_SCOPE_AGENT);
        } else {
            while (__hip_atomic_load(gen, __ATOMIC_ACQUIRE, __HIP_MEMORY_SCOPE_AGENT) == g)
                __builtin_amdgcn_s_sleep(2);
        }
    }
    __syncthreads();
    __threadfence();            // acquire: discard stale cached lines
}

// ============ phase bodies (verified round-3 logic) ========

__device__ __forceinline__ void dev_prep_item(int i,
    const float* __restrict__ x, ushort_t* __restrict__ xb, int n8,
    const float* __restrict__ W0, const float* __restrict__ W1,
    const float* __restrict__ W2, const float* __restrict__ W3,
    ushort_t* __restrict__ T0, ushort_t* __restrict__ T1,
    ushort_t* __restrict__ T2, ushort_t* __restrict__ T3)
{
    if (i < n8) {
        const float4* p = (const float4*)(x + (size_t)i * 8);
        float4 a = p[0], b = p[1];
        uint4 o;
        o.x = pack2(a.x, a.y); o.y = pack2(a.z, a.w);
        o.z = pack2(b.x, b.y); o.w = pack2(b.z, b.w);
        *(uint4*)(xb + (size_t)i * 8) = o;
    }
    if (i < 49152) {
        int mi = i >> 14;
        int r = i & 16383;
        int n = r >> 7, k = r & 127;
        const float* W = mi == 0 ? W0 : (mi == 1 ? W1 : W2);
        ushort_t* T = mi == 0 ? T0 : (mi == 1 ? T1 : T2);
        T[n * 128 + k] = f2bf(W[k * 128 + n]);
    } else if (i < 49152 + 6144) {
        int r = i - 49152;
        int n = r >> 7, k = r & 127;
        T3[n * 128 + k] = (n < 47) ? f2bf(W3[k * 47 + n]) : (ushort_t)0;
    }
}

__device__ __forceinline__ void dev_bin_chunk(int c, int nc1,
    const int* __restrict__ d1, const int* __restrict__ s1, int n1,
    int2* __restrict__ st1, int* __restrict__ cur1, int scap1,
    const int* __restrict__ d2, const int* __restrict__ s2, int n2,
    int2* __restrict__ st2, int* __restrict__ cur2, int scap2,
    int* bcnt, int* gbase, int t)
{
    const int* dst; const int* src; int nE, scap; int* bincur; int2* stage; int bid;
    if (c < nc1) {
        dst = d1; src = s1; nE = n1; scap = scap1; bincur = cur1; stage = st1;
        bid = c;
    } else {
        dst = d2; src = s2; nE = n2; scap = scap2; bincur = cur2; stage = st2;
        bid = c - nc1;
    }
    bcnt[t] = 0;
    __syncthreads();
    int base = bid * 4096;
    int d[16], s[16], l[16];
#pragma unroll
    for (int i = 0; i < 16; i++) {
        int e = base + t + i * 256;
        if (e < nE) {
            d[i] = dst[e]; s[i] = src[e];
            l[i] = atomicAdd(&bcnt[d[i] >> 8], 1);
        } else d[i] = -1;
    }
    __syncthreads();
    if (bcnt[t]) gbase[t] = atomicAdd(&bincur[t], bcnt[t]);
    __syncthreads();
#pragma unroll
    for (int i = 0; i < 16; i++) {
        if (d[i] >= 0) {
            int b = d[i] >> 8;
            int slot = gbase[b] + l[i];
            if (slot < scap) stage[(size_t)b * scap + slot] = make_int2(d[i], s[i]);
        }
    }
    __syncthreads();
}

__device__ __forceinline__ void dev_csr_bin(int c, int NB,
    const int* __restrict__ cur1, const int2* __restrict__ st1, int scap1,
    int* __restrict__ cnt1, int* __restrict__ rp1, int* __restrict__ pk1,
    const int* __restrict__ cur2, const int2* __restrict__ st2, int scap2,
    int* __restrict__ cnt2, int* __restrict__ rp2, int* __restrict__ pk2,
    int* sc, int* wcur, int t)
{
    const int* bincur; const int2* stage; int scap;
    int* cnt; int* rowptr; int* packed; int b;
    if (c < NB) {
        bincur = cur1; stage = st1; scap = scap1;
        cnt = cnt1; rowptr = rp1; packed = pk1; b = c;
    } else {
        bincur = cur2; stage = st2; scap = scap2;
        cnt = cnt2; rowptr = rp2; packed = pk2; b = c - NB;
    }
    int m = bincur[b]; if (m > scap) m = scap;
    const int2* st = stage + (size_t)b * scap;
    sc[t] = 0;
    __syncthreads();
    for (int e = t; e < m; e += 256) atomicAdd(&sc[st[e].x & 255], 1);
    __syncthreads();
    int v = sc[t];
    __syncthreads();
    sc[t] = v;
    __syncthreads();
    for (int off = 1; off < 256; off <<= 1) {
        int y = (t >= off) ? sc[t - off] : 0;
        __syncthreads();
        sc[t] += y;
        __syncthreads();
    }
    int excl = sc[t] - v;
    cnt[b * 256 + t] = v;
    rowptr[b * 256 + t] = b * scap + excl;
    wcur[t] = excl;
    __syncthreads();
    int* pk = packed + (size_t)b * scap;
    for (int e = t; e < m; e += 256) {
        int2 p2 = st[e];
        int slot = atomicAdd(&wcur[p2.x & 255], 1);
        pk[slot] = p2.y;
    }
    __syncthreads();
}

// ======== graphbuild: [prep || bin] -> barrier -> csr (one dispatch) =====
__global__ __launch_bounds__(256) void graphbuild(
    const float* __restrict__ x, ushort_t* __restrict__ xb, int n8,
    const float* __restrict__ W0, const float* __restrict__ W1,
    const float* __restrict__ W2, const float* __restrict__ W3,
    ushort_t* __restrict__ T0, ushort_t* __restrict__ T1,
    ushort_t* __restrict__ T2, ushort_t* __restrict__ T3,
    const int* __restrict__ ego, int nEgo,
    const int* __restrict__ edge, int nEdge,
    int* __restrict__ bincur,
    int2* __restrict__ st_ego, int2* __restrict__ st_edge,
    int* __restrict__ cnt_ego, int* __restrict__ rp_ego, int* __restrict__ pk_ego,
    int* __restrict__ cnt_edge, int* __restrict__ rp_edge, int* __restrict__ pk_edge,
    int NB, int* __restrict__ bar, int* __restrict__ gen)
{
    __shared__ int sA[256], sB[256];
    int t = threadIdx.x, bid = blockIdx.x;
    int gsz = gridDim.x * 256;

    // P0: prep (bf16 convert + weight transpose); no shared deps with bin
    for (int i = bid * 256 + t; i < n8; i += gsz)
        dev_prep_item(i, x, xb, n8, W0, W1, W2, W3, T0, T1, T2, T3);

    // P1: bin edges of both graphs (bincur pre-zeroed by zeroK dispatch)
    int nc1 = (nEgo + 4095) >> 12, nc2 = (nEdge + 4095) >> 12;
    for (int c = bid; c < nc1 + nc2; c += gridDim.x)
        dev_bin_chunk(c, nc1,
                      ego, ego + nEgo, nEgo, st_ego, bincur, SCAP_EGO,
                      edge + nEdge, edge, nEdge, st_edge, bincur + 256, SCAP_E,
                      sA, sB, t);

    grid_barrier(bar, gen, t);

    // P2: per-bin counting sort -> packed CSR
    for (int c = bid; c < 2 * NB; c += gridDim.x)
        dev_csr_bin(c, NB,
                    bincur, st_ego, SCAP_EGO, cnt_ego, rp_ego, pk_ego,
                    bincur + 256, st_edge, SCAP_E, cnt_edge, rp_edge, pk_edge,
                    sA, sB, t);
}

// ======== fused gather + MFMA GEMM 128->128 + relu, 16 rows/block ========
// Round-3 verified body + B-fragment hoist: the wave's 8 B frags are loaded
// from WT after the As store but BEFORE __syncthreads, so the global loads
// fly during the barrier wait instead of stalling the MFMA phase.
template<int SELF>
__global__ __launch_bounds__(256, 8) void fused16(
    const ushort_t* __restrict__ X,
    const int* __restrict__ cnt, const int* __restrict__ rowptr,
    const int* __restrict__ packed,
    const ushort_t* __restrict__ WT, const float* __restrict__ bias,
    ushort_t* __restrict__ outb, int nrows, float scale)
{
    __shared__ ushort_t As[16][136];
    int t = threadIdx.x;
    int g = t >> 4, lane = t & 15;
    int blockBase = blockIdx.x * 16;
    int n = blockBase + g;
    const ushort_t* base = X + lane * 8;
    float a[8];
#pragma unroll
    for (int i = 0; i < 8; i++) a[i] = 0.f;
    if (n < nrows) {
        int len = cnt[n];
        const int* row = packed + rowptr[n];
        int e = 0;
        for (; e + 3 < len; e += 4) {
            uint4 w0 = *(const uint4*)(base + (size_t)row[e] * 128);
            uint4 w1 = *(const uint4*)(base + (size_t)row[e + 1] * 128);
            uint4 w2 = *(const uint4*)(base + (size_t)row[e + 2] * 128);
            uint4 w3 = *(const uint4*)(base + (size_t)row[e + 3] * 128);
            a[0] += lo16(w0.x) + lo16(w1.x) + lo16(w2.x) + lo16(w3.x);
            a[1] += hi16(w0.x) + hi16(w1.x) + hi16(w2.x) + hi16(w3.x);
            a[2] += lo16(w0.y) + lo16(w1.y) + lo16(w2.y) + lo16(w3.y);
            a[3] += hi16(w0.y) + hi16(w1.y) + hi16(w2.y) + hi16(w3.y);
            a[4] += lo16(w0.z) + lo16(w1.z) + lo16(w2.z) + lo16(w3.z);
            a[5] += hi16(w0.z) + hi16(w1.z) + hi16(w2.z) + hi16(w3.z);
            a[6] += lo16(w0.w) + lo16(w1.w) + lo16(w2.w) + lo16(w3.w);
            a[7] += hi16(w0.w) + hi16(w1.w) + hi16(w2.w) + hi16(w3.w);
        }
        for (; e < len; e++) {
            uint4 w = *(const uint4*)(base + (size_t)row[e] * 128);
            a[0] += lo16(w.x); a[1] += hi16(w.x);
            a[2] += lo16(w.y); a[3] += hi16(w.y);
            a[4] += lo16(w.z); a[5] += hi16(w.z);
            a[6] += lo16(w.w); a[7] += hi16(w.w);
        }
        if (SELF) {
            uint4 w = *(const uint4*)(base + (size_t)n * 128);
            a[0] += lo16(w.x); a[1] += hi16(w.x);
            a[2] += lo16(w.y); a[3] += hi16(w.y);
            a[4] += lo16(w.z); a[5] += hi16(w.z);
            a[6] += lo16(w.w); a[7] += hi16(w.w);
        }
    }
    uint4 o;
    o.x = pack2(a[0] * scale, a[1] * scale);
    o.y = pack2(a[2] * scale, a[3] * scale);
    o.z = pack2(a[4] * scale, a[5] * scale);
    o.w = pack2(a[6] * scale, a[7] * scale);
    *(uint4*)&As[g][lane * 8] = o;
    // ---- B-fragment hoist (issue before the barrier) ----
    int wave = t >> 6, l64 = t & 63;
    int m = l64 & 15, quad = l64 >> 4;
    bf16x8 bfr[2][4];
#pragma unroll
    for (int j = 0; j < 2; j++) {
        int ct = wave * 2 + j;
#pragma unroll
        for (int kt = 0; kt < 4; kt++)
            bfr[j][kt] = *(const bf16x8*)(WT + (size_t)(ct * 16 + m) * 128
                                             + kt * 32 + quad * 8);
    }
    __syncthreads();
    // ---- MFMA phase: 16 rows x 128 cols; wave w -> col-tiles 2w, 2w+1 ----
    bf16x8 afr[4];
#pragma unroll
    for (int kt = 0; kt < 4; kt++)
        afr[kt] = *(const bf16x8*)&As[m][kt * 32 + quad * 8];
    f32x4 acc[2];
#pragma unroll
    for (int j = 0; j < 2; j++) acc[j] = (f32x4){0.f, 0.f, 0.f, 0.f};
#pragma unroll
    for (int j = 0; j < 2; j++) {
#pragma unroll
        for (int kt = 0; kt < 4; kt++)
            acc[j] = __builtin_amdgcn_mfma_f32_16x16x32_bf16(afr[kt], bfr[j][kt], acc[j], 0, 0, 0);
    }
#pragma unroll
    for (int j = 0; j < 2; j++) {
        int col = (wave * 2 + j) * 16 + m;
        float bb = bias[col];
#pragma unroll
        for (int r = 0; r < 4; r++) {
            int row = blockBase + quad * 4 + r;
            if (row < nrows) {
                float v = acc[j][r] + bb;
                v = fmaxf(v, 0.f);
                outb[(size_t)row * 128 + col] = f2bf(v);
            }
        }
    }
}

// ======== fused gather + MFMA 128->47 + log_softmax, 16 rows/block ========
__global__ __launch_bounds__(256, 8) void fused47(
    const ushort_t* __restrict__ X,
    const int* __restrict__ cnt, const int* __restrict__ rowptr,
    const int* __restrict__ packed,
    const ushort_t* __restrict__ WT, const float* __restrict__ bias,
    float* __restrict__ out, int nrows)
{
    __shared__ ushort_t As[16][136];
    int t = threadIdx.x;
    int g = t >> 4, lane = t & 15;
    int blockBase = blockIdx.x * 16;
    int n = blockBase + g;
    const ushort_t* base = X + lane * 8;
    float a[8];
#pragma unroll
    for (int i = 0; i < 8; i++) a[i] = 0.f;
    if (n < nrows) {
        int len = cnt[n];
        const int* row = packed + rowptr[n];
        int e = 0;
        for (; e + 3 < len; e += 4) {
            uint4 w0 = *(const uint4*)(base + (size_t)row[e] * 128);
            uint4 w1 = *(const uint4*)(base + (size_t)row[e + 1] * 128);
            uint4 w2 = *(const uint4*)(base + (size_t)row[e + 2] * 128);
            uint4 w3 = *(const uint4*)(base + (size_t)row[e + 3] * 128);
            a[0] += lo16(w0.x) + lo16(w1.x) + lo16(w2.x) + lo16(w3.x);
            a[1] += hi16(w0.x) + hi16(w1.x) + hi16(w2.x) + hi16(w3.x);
            a[2] += lo16(w0.y) + lo16(w1.y) + lo16(w2.y) + lo16(w3.y);
            a[3] += hi16(w0.y) + hi16(w1.y) + hi16(w2.y) + hi16(w3.y);
            a[4] += lo16(w0.z) + lo16(w1.z) + lo16(w2.z) + lo16(w3.z);
            a[5] += hi16(w0.z) + hi16(w1.z) + hi16(w2.z) + hi16(w3.z);
            a[6] += lo16(w0.w) + lo16(w1.w) + lo16(w2.w) + lo16(w3.w);
            a[7] += hi16(w0.w) + hi16(w1.w) + hi16(w2.w) + hi16(w3.w);
        }
        for (; e < len; e++) {
            uint4 w = *(const uint4*)(base + (size_t)row[e] * 128);
            a[0] += lo16(w.x); a[1] += hi16(w.x);
            a[2] += lo16(w.y); a[3] += hi16(w.y);
            a[4] += lo16(w.z); a[5] += hi16(w.z);
            a[6] += lo16(w.w); a[7] += hi16(w.w);
        }
        // GIN self term
        uint4 w = *(const uint4*)(base + (size_t)n * 128);
        a[0] += lo16(w.x); a[1] += hi16(w.x);
        a[2] += lo16(w.y); a[3] += hi16(w.y);
        a[4] += lo16(w.z); a[5] += hi16(w.z);
        a[6] += lo16(w.w); a[7] += hi16(w.w);
    }
    uint4 o;
    o.x = pack2(a[0], a[1]);
    o.y = pack2(a[2], a[3]);
    o.z = pack2(a[4], a[5]);
    o.w = pack2(a[6], a[7]);
    *(uint4*)&As[g][lane * 8] = o;
    __syncthreads();
    // ---- MFMA + log_softmax: wave 0 handles all 3 col-tiles (47 cols) ----
    int wave = t >> 6;
    if (wave != 0) return;
    int l64 = t & 63;
    int m = l64 & 15, quad = l64 >> 4;
    bf16x8 afr[4];
#pragma unroll
    for (int kt = 0; kt < 4; kt++)
        afr[kt] = *(const bf16x8*)&As[m][kt * 32 + quad * 8];
    f32x4 acc[3];
#pragma unroll
    for (int ct = 0; ct < 3; ct++) acc[ct] = (f32x4){0.f, 0.f, 0.f, 0.f};
#pragma unroll
    for (int ct = 0; ct < 3; ct++) {
#pragma unroll
        for (int kt = 0; kt < 4; kt++) {
            bf16x8 b = *(const bf16x8*)(WT + (size_t)(ct * 16 + m) * 128
                                           + kt * 32 + quad * 8);
            acc[ct] = __builtin_amdgcn_mfma_f32_16x16x32_bf16(afr[kt], b, acc[ct], 0, 0, 0);
        }
    }
    int c0 = m, c1 = 16 + m, c2 = 32 + m;
    bool has2 = (c2 < 47);
    float b0 = bias[c0], b1 = bias[c1], b2 = has2 ? bias[c2] : 0.f;
#pragma unroll
    for (int r = 0; r < 4; r++) {
        int row = blockBase + quad * 4 + r;
        float v0 = acc[0][r] + b0;
        float v1 = acc[1][r] + b1;
        float v2 = has2 ? (acc[2][r] + b2) : -INFINITY;
        float mx = fmaxf(fmaxf(v0, v1), v2);
#pragma unroll
        for (int off = 8; off; off >>= 1) mx = fmaxf(mx, __shfl_xor(mx, off, 64));
        float s = __expf(v0 - mx) + __expf(v1 - mx) + (has2 ? __expf(v2 - mx) : 0.f);
#pragma unroll
        for (int off = 8; off; off >>= 1) s += __shfl_xor(s, off, 64);
        float lse = mx + __logf(s);
        if (row < nrows) {
            float* o2 = out + (size_t)row * 47;
            o2[c0] = v0 - lse;
            o2[c1] = v1 - lse;
            if (has2) o2[c2] = v2 - lse;
        }
    }
}

// ============================== host ======================================
extern "C" void kernel_launch(void* const* d_in, const int* in_sizes, int n_in,
                              void* d_out, int out_size, void* d_ws, size_t ws_size,
                              hipStream_t stream) {
    const float* x_in   = (const float*)d_in[0];    // fp32 [N,128]
    const int*   edge   = (const int*)d_in[1];      // [2,E]  row0=src row1=tgt
    const int*   ego    = (const int*)d_in[2];      // [2,EGO_E] row0=dst row1=src
    const float* W_ego0 = (const float*)d_in[3];
    const float* b_ego0 = (const float*)d_in[4];
    const float* W_gin0 = (const float*)d_in[5];
    const float* b_gin0 = (const float*)d_in[6];
    const float* W_ego1 = (const float*)d_in[7];
    const float* b_ego1 = (const float*)d_in[8];
    const float* W_gin1 = (const float*)d_in[9];
    const float* b_gin1 = (const float*)d_in[10];
    float* out = (float*)d_out;                     // fp32 [N,47]

    const int N     = in_sizes[0] / 128;
    const int E     = in_sizes[1] / 2;
    const int EGO_E = in_sizes[2] / 2;
    const float invN = 1.0f / (float)N;
    const int NB    = (N + 255) >> 8;               // 256-node bins
    const int n8    = N * 128 / 8;

    // ---- workspace layout (~69 MB) ----
    const size_t NBELEM = (size_t)N * 128;
    ushort_t* Xb = (ushort_t*)d_ws;                 // bf16 [N,128]
    ushort_t* G  = Xb + NBELEM;                     // ping
    ushort_t* H  = G + NBELEM;                      // pong
    ushort_t* T0 = H + NBELEM;
    ushort_t* T1 = T0 + 16384;
    ushort_t* T2 = T1 + 16384;
    ushort_t* T3 = T2 + 16384;                      // [48][128]
    int* ip = (int*)(T3 + 6144);
    int* cnt_ego   = ip;             ip += NB * 256;
    int* rp_ego    = ip;             ip += NB * 256;
    int* cnt_edge  = ip;             ip += NB * 256;
    int* rp_edge   = ip;             ip += NB * 256;
    int* bincur    = ip;             ip += 512;     // [0..255]=ego, [256..511]=edge
    int* bar       = ip;             ip += 2;       // [0]=counter, [1]=generation
    ip += 2;                                        // pad to 16B
    int2* stage_ego  = (int2*)ip;    ip += (size_t)NB * SCAP_EGO * 2;
    int*  pk_ego     = ip;           ip += (size_t)NB * SCAP_EGO;
    int2* stage_edge = (int2*)ip;    ip += (size_t)NB * SCAP_E * 2;
    int*  pk_edge    = ip;           ip += (size_t)NB * SCAP_E;

    const int gFused = (N + 15) / 16;
    const int gBuild = 896;     // >> #chunks coverage, << co-residency capacity

    // ---- 6 dispatches total ----
    zeroK<<<1, 256, 0, stream>>>(bincur);   // bincur[512] + bar/gen
    graphbuild<<<gBuild, 256, 0, stream>>>(
        x_in, Xb, n8, W_ego0, W_gin0, W_ego1, W_gin1, T0, T1, T2, T3,
        ego, EGO_E, edge, E, bincur,
        stage_ego, stage_edge,
        cnt_ego, rp_ego, pk_ego, cnt_edge, rp_edge, pk_edge,
        NB, bar, bar + 1);
    // layer 0: Ego conv -> relu
    fused16<0><<<gFused, 256, 0, stream>>>(Xb, cnt_ego, rp_ego, pk_ego,
                                           T0, b_ego0, H, N, invN);
    // layer 0: GIN (self + aggr) -> relu
    fused16<1><<<gFused, 256, 0, stream>>>(H, cnt_edge, rp_edge, pk_edge,
                                           T1, b_gin0, G, N, 1.f);
    // layer 1: Ego conv -> relu
    fused16<0><<<gFused, 256, 0, stream>>>(G, cnt_ego, rp_ego, pk_ego,
                                           T2, b_ego1, H, N, invN);
    // layer 1: GIN + fused log_softmax
    fused47<<<gFused, 256, 0, stream>>>(H, cnt_edge, rp_edge, pk_edge,
                                        T3, b_gin1, out, N);
}

// Round 7
// 309.633 us; speedup vs baseline: 3.6349x; 2.3062x over previous
//
#include <hip/hip_runtime.h>

#define SCAP_EGO 8192   // staging cap per 256-node bin (mean 6144)
#define SCAP_E   4096   // mean 3072

typedef unsigned short ushort_t;
typedef unsigned int uint_t;
typedef __attribute__((ext_vector_type(8))) short bf16x8;
typedef __attribute__((ext_vector_type(4))) float f32x4;

__device__ inline float lo16(uint_t u) { return __uint_as_float(u << 16); }
__device__ inline float hi16(uint_t u) { return __uint_as_float(u & 0xFFFF0000u); }
__device__ inline ushort_t f2bf(float f) {
    uint_t i = __float_as_uint(f);
    return (ushort_t)((i + 0x7FFFu + ((i >> 16) & 1u)) >> 16);
}
__device__ inline uint_t pack2(float a, float b) {
    return (uint_t)f2bf(a) | ((uint_t)f2bf(b) << 16);
}

// ======== prep: x fp32->bf16, weights fp32->bf16 W^T, zero cursors ========
__global__ __launch_bounds__(256) void prep(
    const float* __restrict__ x, ushort_t* __restrict__ xb, int n8,
    const float* __restrict__ W0, const float* __restrict__ W1,
    const float* __restrict__ W2, const float* __restrict__ W3,
    ushort_t* __restrict__ T0, ushort_t* __restrict__ T1,
    ushort_t* __restrict__ T2, ushort_t* __restrict__ T3,
    int* __restrict__ z)
{
    int i = blockIdx.x * 256 + threadIdx.x;
    if (i < 128) ((int4*)z)[i] = make_int4(0, 0, 0, 0);
    if (i < n8) {
        const float4* p = (const float4*)(x + (size_t)i * 8);
        float4 a = p[0], b = p[1];
        uint4 o;
        o.x = pack2(a.x, a.y); o.y = pack2(a.z, a.w);
        o.z = pack2(b.x, b.y); o.w = pack2(b.z, b.w);
        *(uint4*)(xb + (size_t)i * 8) = o;
    }
    if (i < 49152) {
        int mi = i >> 14;
        int r = i & 16383;
        int n = r >> 7, k = r & 127;
        const float* W = mi == 0 ? W0 : (mi == 1 ? W1 : W2);
        ushort_t* T = mi == 0 ? T0 : (mi == 1 ? T1 : T2);
        T[n * 128 + k] = f2bf(W[k * 128 + n]);
    } else if (i < 49152 + 6144) {
        int r = i - 49152;
        int n = r >> 7, k = r & 127;
        T3[n * 128 + k] = (n < 47) ? f2bf(W3[k * 47 + n]) : (ushort_t)0;
    }
}

// ======== merged phase A: bin edges of BOTH graphs (block-range branch) ====
__global__ __launch_bounds__(256) void bin_edges2(
    const int* __restrict__ d1, const int* __restrict__ s1, int n1, int nb1,
    int* __restrict__ cur1, int2* __restrict__ st1, int scap1,
    const int* __restrict__ d2, const int* __restrict__ s2, int n2,
    int* __restrict__ cur2, int2* __restrict__ st2, int scap2)
{
    const int* dst; const int* src; int nE, scap; int* bincur; int2* stage; int bid;
    if (blockIdx.x < (uint_t)nb1) {
        dst = d1; src = s1; nE = n1; scap = scap1; bincur = cur1; stage = st1;
        bid = blockIdx.x;
    } else {
        dst = d2; src = s2; nE = n2; scap = scap2; bincur = cur2; stage = st2;
        bid = blockIdx.x - nb1;
    }
    __shared__ int bcnt[256];
    __shared__ int gbase[256];
    int t = threadIdx.x;
    bcnt[t] = 0;
    __syncthreads();
    int base = bid * 4096;
    int d[16], s[16], l[16];
#pragma unroll
    for (int i = 0; i < 16; i++) {
        int e = base + t + i * 256;
        if (e < nE) {
            d[i] = dst[e]; s[i] = src[e];
            l[i] = atomicAdd(&bcnt[d[i] >> 8], 1);
        } else d[i] = -1;
    }
    __syncthreads();
    if (bcnt[t]) gbase[t] = atomicAdd(&bincur[t], bcnt[t]);
    __syncthreads();
#pragma unroll
    for (int i = 0; i < 16; i++) {
        if (d[i] >= 0) {
            int b = d[i] >> 8;
            int slot = gbase[b] + l[i];
            if (slot < scap) stage[(size_t)b * scap + slot] = make_int2(d[i], s[i]);
        }
    }
}

// ======== merged phase B: per-bin counting sort -> packed CSR ========
// Also emits a bin-local degree-sorted node permutation (perm): nodes in
// each 256-bin ordered by ascending degree, so every 16-node fused tile
// gets near-equal degrees (kills the barrier-wait on the max-degree node).
__global__ __launch_bounds__(256) void build_csr2(
    const int* __restrict__ cur1, const int2* __restrict__ st1, int scap1,
    int* __restrict__ cnt1, int* __restrict__ rp1, int* __restrict__ pk1,
    int* __restrict__ perm1,
    const int* __restrict__ cur2, const int2* __restrict__ st2, int scap2,
    int* __restrict__ cnt2, int* __restrict__ rp2, int* __restrict__ pk2,
    int* __restrict__ perm2,
    int NB)
{
    const int* bincur; const int2* stage; int scap;
    int* cnt; int* rowptr; int* packed; int* perm; int b;
    if (blockIdx.x < (uint_t)NB) {
        bincur = cur1; stage = st1; scap = scap1;
        cnt = cnt1; rowptr = rp1; packed = pk1; perm = perm1; b = blockIdx.x;
    } else {
        bincur = cur2; stage = st2; scap = scap2;
        cnt = cnt2; rowptr = rp2; packed = pk2; perm = perm2; b = blockIdx.x - NB;
    }
    __shared__ int sc[256];
    __shared__ int wcur[256];
    int t = threadIdx.x;
    int m = bincur[b]; if (m > scap) m = scap;
    const int2* st = stage + (size_t)b * scap;
    sc[t] = 0;
    __syncthreads();
    for (int e = t; e < m; e += 256) atomicAdd(&sc[st[e].x & 255], 1);
    __syncthreads();
    int v = sc[t];                       // degree of node b*256+t
    __syncthreads();
    sc[t] = v;
    __syncthreads();
    for (int off = 1; off < 256; off <<= 1) {
        int y = (t >= off) ? sc[t - off] : 0;
        __syncthreads();
        sc[t] += y;
        __syncthreads();
    }
    int excl = sc[t] - v;
    cnt[b * 256 + t] = v;
    rowptr[b * 256 + t] = b * scap + excl;
    wcur[t] = excl;
    __syncthreads();
    int* pk = packed + (size_t)b * scap;
    for (int e = t; e < m; e += 256) {
        int2 p = st[e];
        int slot = atomicAdd(&wcur[p.x & 255], 1);
        pk[slot] = p.y;
    }
    __syncthreads();
    // ---- bin-local degree sort -> perm ----
    sc[t] = 0;
    __syncthreads();
    int dcap = v > 255 ? 255 : v;
    atomicAdd(&sc[dcap], 1);             // histogram by degree
    __syncthreads();
    int h = sc[t];
    __syncthreads();
    sc[t] = h;
    __syncthreads();
    for (int off = 1; off < 256; off <<= 1) {
        int y = (t >= off) ? sc[t - off] : 0;
        __syncthreads();
        sc[t] += y;
        __syncthreads();
    }
    wcur[t] = sc[t] - h;                 // exclusive prefix by degree
    __syncthreads();
    int rank = atomicAdd(&wcur[dcap], 1);
    perm[b * 256 + rank] = b * 256 + t;
}

// ======== fused gather + MFMA GEMM 128->128 + relu, 16 rows/block ========
// Round-3 verified body + degree-balanced node permutation + half B-hoist
// (first col-tile's B frags loaded pre-barrier; +16 VGPR, stays <=64).
template<int SELF>
__global__ __launch_bounds__(256, 8) void fused16(
    const ushort_t* __restrict__ X,
    const int* __restrict__ cnt, const int* __restrict__ rowptr,
    const int* __restrict__ packed, const int* __restrict__ perm,
    const ushort_t* __restrict__ WT, const float* __restrict__ bias,
    ushort_t* __restrict__ outb, int nrows, float scale)
{
    __shared__ ushort_t As[16][136];
    __shared__ int sP[16];
    int t = threadIdx.x;
    int g = t >> 4, lane = t & 15;
    int blockBase = blockIdx.x * 16;
    int n = perm[blockBase + g];         // degree-balanced node (may be >= nrows)
    if (lane == 0) sP[g] = n;
    const ushort_t* base = X + lane * 8;
    float a[8];
#pragma unroll
    for (int i = 0; i < 8; i++) a[i] = 0.f;
    if (n < nrows) {
        int len = cnt[n];
        const int* row = packed + rowptr[n];
        int e = 0;
        for (; e + 3 < len; e += 4) {
            uint4 w0 = *(const uint4*)(base + (size_t)row[e] * 128);
            uint4 w1 = *(const uint4*)(base + (size_t)row[e + 1] * 128);
            uint4 w2 = *(const uint4*)(base + (size_t)row[e + 2] * 128);
            uint4 w3 = *(const uint4*)(base + (size_t)row[e + 3] * 128);
            a[0] += lo16(w0.x) + lo16(w1.x) + lo16(w2.x) + lo16(w3.x);
            a[1] += hi16(w0.x) + hi16(w1.x) + hi16(w2.x) + hi16(w3.x);
            a[2] += lo16(w0.y) + lo16(w1.y) + lo16(w2.y) + lo16(w3.y);
            a[3] += hi16(w0.y) + hi16(w1.y) + hi16(w2.y) + hi16(w3.y);
            a[4] += lo16(w0.z) + lo16(w1.z) + lo16(w2.z) + lo16(w3.z);
            a[5] += hi16(w0.z) + hi16(w1.z) + hi16(w2.z) + hi16(w3.z);
            a[6] += lo16(w0.w) + lo16(w1.w) + lo16(w2.w) + lo16(w3.w);
            a[7] += hi16(w0.w) + hi16(w1.w) + hi16(w2.w) + hi16(w3.w);
        }
        for (; e < len; e++) {
            uint4 w = *(const uint4*)(base + (size_t)row[e] * 128);
            a[0] += lo16(w.x); a[1] += hi16(w.x);
            a[2] += lo16(w.y); a[3] += hi16(w.y);
            a[4] += lo16(w.z); a[5] += hi16(w.z);
            a[6] += lo16(w.w); a[7] += hi16(w.w);
        }
        if (SELF) {
            uint4 w = *(const uint4*)(base + (size_t)n * 128);
            a[0] += lo16(w.x); a[1] += hi16(w.x);
            a[2] += lo16(w.y); a[3] += hi16(w.y);
            a[4] += lo16(w.z); a[5] += hi16(w.z);
            a[6] += lo16(w.w); a[7] += hi16(w.w);
        }
    }
    uint4 o;
    o.x = pack2(a[0] * scale, a[1] * scale);
    o.y = pack2(a[2] * scale, a[3] * scale);
    o.z = pack2(a[4] * scale, a[5] * scale);
    o.w = pack2(a[6] * scale, a[7] * scale);
    *(uint4*)&As[g][lane * 8] = o;
    // ---- half B-hoist: first col-tile's frags issue before the barrier ----
    int wave = t >> 6, l64 = t & 63;
    int m = l64 & 15, quad = l64 >> 4;
    bf16x8 bfr0[4];
#pragma unroll
    for (int kt = 0; kt < 4; kt++)
        bfr0[kt] = *(const bf16x8*)(WT + (size_t)((wave * 2) * 16 + m) * 128
                                       + kt * 32 + quad * 8);
    __syncthreads();
    // ---- MFMA phase: 16 rows x 128 cols; wave w -> col-tiles 2w, 2w+1 ----
    bf16x8 afr[4];
#pragma unroll
    for (int kt = 0; kt < 4; kt++)
        afr[kt] = *(const bf16x8*)&As[m][kt * 32 + quad * 8];
    f32x4 acc[2];
#pragma unroll
    for (int j = 0; j < 2; j++) acc[j] = (f32x4){0.f, 0.f, 0.f, 0.f};
#pragma unroll
    for (int kt = 0; kt < 4; kt++)
        acc[0] = __builtin_amdgcn_mfma_f32_16x16x32_bf16(afr[kt], bfr0[kt], acc[0], 0, 0, 0);
#pragma unroll
    for (int kt = 0; kt < 4; kt++) {
        bf16x8 b = *(const bf16x8*)(WT + (size_t)((wave * 2 + 1) * 16 + m) * 128
                                       + kt * 32 + quad * 8);
        acc[1] = __builtin_amdgcn_mfma_f32_16x16x32_bf16(afr[kt], b, acc[1], 0, 0, 0);
    }
#pragma unroll
    for (int j = 0; j < 2; j++) {
        int col = (wave * 2 + j) * 16 + m;
        float bb = bias[col];
#pragma unroll
        for (int r = 0; r < 4; r++) {
            int rr = sP[quad * 4 + r];
            if (rr < nrows) {
                float v = acc[j][r] + bb;
                v = fmaxf(v, 0.f);
                outb[(size_t)rr * 128 + col] = f2bf(v);
            }
        }
    }
}

// ======== fused gather + MFMA 128->47 + log_softmax, 16 rows/block ========
__global__ __launch_bounds__(256, 8) void fused47(
    const ushort_t* __restrict__ X,
    const int* __restrict__ cnt, const int* __restrict__ rowptr,
    const int* __restrict__ packed, const int* __restrict__ perm,
    const ushort_t* __restrict__ WT, const float* __restrict__ bias,
    float* __restrict__ out, int nrows)
{
    __shared__ ushort_t As[16][136];
    __shared__ int sP[16];
    int t = threadIdx.x;
    int g = t >> 4, lane = t & 15;
    int blockBase = blockIdx.x * 16;
    int n = perm[blockBase + g];
    if (lane == 0) sP[g] = n;
    const ushort_t* base = X + lane * 8;
    float a[8];
#pragma unroll
    for (int i = 0; i < 8; i++) a[i] = 0.f;
    if (n < nrows) {
        int len = cnt[n];
        const int* row = packed + rowptr[n];
        int e = 0;
        for (; e + 3 < len; e += 4) {
            uint4 w0 = *(const uint4*)(base + (size_t)row[e] * 128);
            uint4 w1 = *(const uint4*)(base + (size_t)row[e + 1] * 128);
            uint4 w2 = *(const uint4*)(base + (size_t)row[e + 2] * 128);
            uint4 w3 = *(const uint4*)(base + (size_t)row[e + 3] * 128);
            a[0] += lo16(w0.x) + lo16(w1.x) + lo16(w2.x) + lo16(w3.x);
            a[1] += hi16(w0.x) + hi16(w1.x) + hi16(w2.x) + hi16(w3.x);
            a[2] += lo16(w0.y) + lo16(w1.y) + lo16(w2.y) + lo16(w3.y);
            a[3] += hi16(w0.y) + hi16(w1.y) + hi16(w2.y) + hi16(w3.y);
            a[4] += lo16(w0.z) + lo16(w1.z) + lo16(w2.z) + lo16(w3.z);
            a[5] += hi16(w0.z) + hi16(w1.z) + hi16(w2.z) + hi16(w3.z);
            a[6] += lo16(w0.w) + lo16(w1.w) + lo16(w2.w) + lo16(w3.w);
            a[7] += hi16(w0.w) + hi16(w1.w) + hi16(w2.w) + hi16(w3.w);
        }
        for (; e < len; e++) {
            uint4 w = *(const uint4*)(base + (size_t)row[e] * 128);
            a[0] += lo16(w.x); a[1] += hi16(w.x);
            a[2] += lo16(w.y); a[3] += hi16(w.y);
            a[4] += lo16(w.z); a[5] += hi16(w.z);
            a[6] += lo16(w.w); a[7] += hi16(w.w);
        }
        // GIN self term
        uint4 w = *(const uint4*)(base + (size_t)n * 128);
        a[0] += lo16(w.x); a[1] += hi16(w.x);
        a[2] += lo16(w.y); a[3] += hi16(w.y);
        a[4] += lo16(w.z); a[5] += hi16(w.z);
        a[6] += lo16(w.w); a[7] += hi16(w.w);
    }
    uint4 o;
    o.x = pack2(a[0], a[1]);
    o.y = pack2(a[2], a[3]);
    o.z = pack2(a[4], a[5]);
    o.w = pack2(a[6], a[7]);
    *(uint4*)&As[g][lane * 8] = o;
    __syncthreads();
    // ---- MFMA + log_softmax: wave 0 handles all 3 col-tiles (47 cols) ----
    int wave = t >> 6;
    if (wave != 0) return;
    int l64 = t & 63;
    int m = l64 & 15, quad = l64 >> 4;
    bf16x8 afr[4];
#pragma unroll
    for (int kt = 0; kt < 4; kt++)
        afr[kt] = *(const bf16x8*)&As[m][kt * 32 + quad * 8];
    f32x4 acc[3];
#pragma unroll
    for (int ct = 0; ct < 3; ct++) acc[ct] = (f32x4){0.f, 0.f, 0.f, 0.f};
#pragma unroll
    for (int ct = 0; ct < 3; ct++) {
#pragma unroll
        for (int kt = 0; kt < 4; kt++) {
            bf16x8 b = *(const bf16x8*)(WT + (size_t)(ct * 16 + m) * 128
                                           + kt * 32 + quad * 8);
            acc[ct] = __builtin_amdgcn_mfma_f32_16x16x32_bf16(afr[kt], b, acc[ct], 0, 0, 0);
        }
    }
    int c0 = m, c1 = 16 + m, c2 = 32 + m;
    bool has2 = (c2 < 47);
    float b0 = bias[c0], b1 = bias[c1], b2 = has2 ? bias[c2] : 0.f;
#pragma unroll
    for (int r = 0; r < 4; r++) {
        int rr = sP[quad * 4 + r];
        float v0 = acc[0][r] + b0;
        float v1 = acc[1][r] + b1;
        float v2 = has2 ? (acc[2][r] + b2) : -INFINITY;
        float mx = fmaxf(fmaxf(v0, v1), v2);
#pragma unroll
        for (int off = 8; off; off >>= 1) mx = fmaxf(mx, __shfl_xor(mx, off, 64));
        float s = __expf(v0 - mx) + __expf(v1 - mx) + (has2 ? __expf(v2 - mx) : 0.f);
#pragma unroll
        for (int off = 8; off; off >>= 1) s += __shfl_xor(s, off, 64);
        float lse = mx + __logf(s);
        if (rr < nrows) {
            float* o2 = out + (size_t)rr * 47;
            o2[c0] = v0 - lse;
            o2[c1] = v1 - lse;
            if (has2) o2[c2] = v2 - lse;
        }
    }
}

extern "C" void kernel_launch(void* const* d_in, const int* in_sizes, int n_in,
                              void* d_out, int out_size, void* d_ws, size_t ws_size,
                              hipStream_t stream) {
    const float* x_in   = (const float*)d_in[0];    // fp32 [N,128]
    const int*   edge   = (const int*)d_in[1];      // [2,E]  row0=src row1=tgt
    const int*   ego    = (const int*)d_in[2];      // [2,EGO_E] row0=dst row1=src
    const float* W_ego0 = (const float*)d_in[3];
    const float* b_ego0 = (const float*)d_in[4];
    const float* W_gin0 = (const float*)d_in[5];
    const float* b_gin0 = (const float*)d_in[6];
    const float* W_ego1 = (const float*)d_in[7];
    const float* b_ego1 = (const float*)d_in[8];
    const float* W_gin1 = (const float*)d_in[9];
    const float* b_gin1 = (const float*)d_in[10];
    float* out = (float*)d_out;                     // fp32 [N,47]

    const int N     = in_sizes[0] / 128;
    const int E     = in_sizes[1] / 2;
    const int EGO_E = in_sizes[2] / 2;
    const float invN = 1.0f / (float)N;
    const int NB    = (N + 255) >> 8;               // 256-node bins

    // ---- workspace layout (~69 MB) ----
    const size_t NBELEM = (size_t)N * 128;
    ushort_t* Xb = (ushort_t*)d_ws;                 // bf16 [N,128]
    ushort_t* G  = Xb + NBELEM;                     // ping
    ushort_t* H  = G + NBELEM;                      // pong
    ushort_t* T0 = H + NBELEM;
    ushort_t* T1 = T0 + 16384;
    ushort_t* T2 = T1 + 16384;
    ushort_t* T3 = T2 + 16384;                      // [48][128]
    int* ip = (int*)(T3 + 6144);
    int* cnt_ego   = ip;             ip += NB * 256;
    int* rp_ego    = ip;             ip += NB * 256;
    int* cnt_edge  = ip;             ip += NB * 256;
    int* rp_edge   = ip;             ip += NB * 256;
    int* perm_ego  = ip;             ip += NB * 256;
    int* perm_edge = ip;             ip += NB * 256;
    int* bincur    = ip;             ip += 512;     // [0..255]=ego, [256..511]=edge
    int2* stage_ego  = (int2*)ip;    ip += (size_t)NB * SCAP_EGO * 2;
    int*  pk_ego     = ip;           ip += (size_t)NB * SCAP_EGO;
    int2* stage_edge = (int2*)ip;    ip += (size_t)NB * SCAP_E * 2;
    int*  pk_edge    = ip;           ip += (size_t)NB * SCAP_E;

    const int gFused  = NB * 16;                    // tiles are bin-aligned
    const int gBinE   = (EGO_E + 4095) / 4096;
    const int gBinF   = (E + 4095) / 4096;
    const int gCvt    = ((N * 128 / 8) + 255) / 256;

    // ---- prep + graph build (3 launches) ----
    prep<<<gCvt, 256, 0, stream>>>(x_in, Xb, N * 128 / 8,
                                   W_ego0, W_gin0, W_ego1, W_gin1,
                                   T0, T1, T2, T3, bincur);
    bin_edges2<<<gBinE + gBinF, 256, 0, stream>>>(
        ego, ego + EGO_E, EGO_E, gBinE, bincur, stage_ego, SCAP_EGO,
        edge + E, edge, E, bincur + 256, stage_edge, SCAP_E);
    build_csr2<<<2 * NB, 256, 0, stream>>>(
        bincur, stage_ego, SCAP_EGO, cnt_ego, rp_ego, pk_ego, perm_ego,
        bincur + 256, stage_edge, SCAP_E, cnt_edge, rp_edge, pk_edge, perm_edge,
        NB);

    // ---- network (4 fused launches) ----
    // layer 0: Ego conv -> relu
    fused16<0><<<gFused, 256, 0, stream>>>(Xb, cnt_ego, rp_ego, pk_ego, perm_ego,
                                           T0, b_ego0, H, N, invN);
    // layer 0: GIN (self + aggr) -> relu
    fused16<1><<<gFused, 256, 0, stream>>>(H, cnt_edge, rp_edge, pk_edge, perm_edge,
                                           T1, b_gin0, G, N, 1.f);
    // layer 1: Ego conv -> relu
    fused16<0><<<gFused, 256, 0, stream>>>(G, cnt_ego, rp_ego, pk_ego, perm_ego,
                                           T2, b_ego1, H, N, invN);
    // layer 1: GIN + fused log_softmax
    fused47<<<gFused, 256, 0, stream>>>(H, cnt_edge, rp_edge, pk_edge, perm_edge,
                                        T3, b_gin1, out, N);
}